// Round 16
// baseline (57.645 us; speedup 1.0000x reference)
//
#include <hip/hip_runtime.h>
#include <hip/hip_bf16.h>
#include <math.h>
#include <cstdint>

#define NUSER 16384   // B*U
#define BB    64
#define UU    256
#define SSLOT 64
#define HD    256
#define KTOT  320
#define DEGS  8
#define DEGU  16

typedef __attribute__((ext_vector_type(8))) short short8;
typedef __attribute__((ext_vector_type(4))) float f32x4;

static __device__ __forceinline__ __hip_bfloat16 f2b(float x) { return __float2bfloat16(x); }
static __device__ __forceinline__ unsigned pack2(float x, float y) {
  union { __hip_bfloat16 h[2]; unsigned u; } cv;
  cv.h[0] = f2b(x); cv.h[1] = f2b(y);
  return cv.u;
}

// ---------------------------------------------------------------------------
// K1 (round-15 verbatim): prep (masks, fragment-packed weights) + layer-1.
// ---------------------------------------------------------------------------
__global__ __launch_bounds__(256) void k_prep_pq(
    const int* __restrict__ dst_u2s, const int* __restrict__ dst_u2u,
    const float* __restrict__ oW2, const float* __restrict__ sW2,
    const float* __restrict__ sW3,
    const float* __restrict__ xu, const float* __restrict__ xs,
    const float* __restrict__ oW1, const float* __restrict__ sW1,
    unsigned long long* __restrict__ connS, unsigned* __restrict__ MSUW,
    __hip_bfloat16* __restrict__ W2F_o, __hip_bfloat16* __restrict__ W2F_s,
    __hip_bfloat16* __restrict__ W3F_s,
    __hip_bfloat16* __restrict__ P_o, __hip_bfloat16* __restrict__ P_s,
    __hip_bfloat16* __restrict__ Q_o, __hip_bfloat16* __restrict__ Q_s) {
  const int t = threadIdx.x;
  if (blockIdx.y == 0) {
    const int blk = blockIdx.x;
    if (blk < 64) {
      const int u = blk * 256 + t;
      unsigned long long ms = 0ull;
      #pragma unroll
      for (int i = 0; i < DEGS; ++i) ms |= 1ull << (dst_u2s[u * DEGS + i] & 63);
      connS[u] = ms;
      unsigned long long m0 = 0, m1 = 0, m2 = 0, m3 = 0;
      #pragma unroll
      for (int i = 0; i < DEGU; ++i) {
        int slot = dst_u2u[u * DEGU + i] & 255;
        unsigned long long bit = 1ull << (slot & 63);
        int w = slot >> 6;
        if (w == 0) m0 |= bit; else if (w == 1) m1 |= bit;
        else if (w == 2) m2 |= bit; else m3 |= bit;
      }
      unsigned* mw = MSUW + (size_t)u * 10;
      uint2* mw2 = (uint2*)mw;
      mw2[0] = make_uint2((unsigned)ms, (unsigned)(ms >> 32));
      mw2[1] = make_uint2((unsigned)m0, (unsigned)(m0 >> 32));
      mw2[2] = make_uint2((unsigned)m1, (unsigned)(m1 >> 32));
      mw2[3] = make_uint2((unsigned)m2, (unsigned)(m2 >> 32));
      mw2[4] = make_uint2((unsigned)m3, (unsigned)(m3 >> 32));
      {
        const int n = blk;
        const int ks = t >> 5, hi = (t >> 3) & 3, e = t & 7;
        const int lane = hi * 16 + (n & 15);
        const size_t idx = (size_t)((((n >> 4) * 8 + ks) * 64 + lane)) * 8 + e;
        W3F_s[idx] = f2b(sW3[(ks * 32 + hi * 8 + e) * SSLOT + n]);
      }
    } else {
      const int n = blk - 64;
      const int ks = t >> 5, hi = (t >> 3) & 3, e = t & 7;
      const int lane = hi * 16 + (n & 15);
      const size_t idx = (size_t)((((n >> 4) * 8 + ks) * 64 + lane)) * 8 + e;
      const int k = ks * 32 + hi * 8 + e;
      W2F_o[idx] = f2b(oW2[k * HD + n]);
      W2F_s[idx] = f2b(sW2[k * HD + n]);
    }
    return;
  }
  // ---- pq body ----
  const int wg = blockIdx.x;
  const int b0 = (blockIdx.y - 1) * 8;
  __shared__ float lx[8 * 16];
  const bool isS = wg < SSLOT;
  const int slot = isS ? wg : wg - SSLOT;
  if (t < 8 * 16) {
    int b = b0 + (t >> 4), d = t & 15;
    lx[t] = isS ? xs[(b * SSLOT + slot) * 16 + d] : xu[(b * UU + slot) * 16 + d];
  }
  __syncthreads();
  float wo[16], wsv[16];
  const int rbase = isS ? slot * 16 : SSLOT * 16 + slot * 16;
  #pragma unroll
  for (int d = 0; d < 16; ++d) {
    wo[d] = oW1[(rbase + d) * HD + t];
    wsv[d] = sW1[(rbase + d) * HD + t];
  }
  __hip_bfloat16* Ro = isS ? P_o : Q_o;
  __hip_bfloat16* Rs = isS ? P_s : Q_s;
  const int rows = isS ? SSLOT : UU;
  #pragma unroll
  for (int bi = 0; bi < 8; ++bi) {
    float ao = 0.f, as = 0.f;
    #pragma unroll
    for (int q = 0; q < 4; ++q) {
      float4 x4 = *(const float4*)&lx[bi * 16 + q * 4];
      ao = fmaf(x4.x, wo[q*4+0], ao); as = fmaf(x4.x, wsv[q*4+0], as);
      ao = fmaf(x4.y, wo[q*4+1], ao); as = fmaf(x4.y, wsv[q*4+1], as);
      ao = fmaf(x4.z, wo[q*4+2], ao); as = fmaf(x4.z, wsv[q*4+2], as);
      ao = fmaf(x4.w, wo[q*4+3], ao); as = fmaf(x4.w, wsv[q*4+3], as);
    }
    Ro[((b0 + bi) * rows + slot) * HD + t] = f2b(ao);
    Rs[((b0 + bi) * rows + slot) * HD + t] = f2b(as);
  }
}

// ---------------------------------------------------------------------------
// K2: h1 via mask-MFMA with FUSED transpose (k_tr folded in; PQT eliminated).
// grid (128,2,2): x=(b<<1)|uh, y=mlp, z=nh. 256 thr.
// Per 64-k chunk: stage P/Q rows [64 k][128 n] coalesced into buf (17.4 KB),
// LDS-transpose into pan[128 n][72 k] (18.4 KB), 2 kt of MFMA. Masks 5 KB.
// ---------------------------------------------------------------------------
__global__ __launch_bounds__(256) void k_h1f(
    const unsigned* __restrict__ MSUW,
    const __hip_bfloat16* __restrict__ P_o, const __hip_bfloat16* __restrict__ P_s,
    const __hip_bfloat16* __restrict__ Q_o, const __hip_bfloat16* __restrict__ Q_s,
    const float* __restrict__ ob1, const float* __restrict__ sb1,
    __hip_bfloat16* __restrict__ h1o, __hip_bfloat16* __restrict__ h1s) {
  const int b = blockIdx.x >> 1, uh = blockIdx.x & 1;
  const int mlp = blockIdx.y, nh = blockIdx.z;
  const int n0 = nh * 128;
  const int t = threadIdx.x;
  const __hip_bfloat16* P = mlp ? P_s : P_o;
  const __hip_bfloat16* Q = mlp ? Q_s : Q_o;
  const float* b1 = mlp ? sb1 : ob1;
  __hip_bfloat16* h1 = mlp ? h1s : h1o;

  __shared__ __align__(16) char smem[17408 + 18432 + 5120];
  short* buf = (short*)smem;                     // [64 k][136] row-major stage
  short* pan = (short*)(smem + 17408);           // [128 n][72] k-major
  unsigned* mskL = (unsigned*)(smem + 35840);    // 1280 u32

  {
    const unsigned* g = MSUW + (size_t)(b * 256 + uh * 128) * 10;
    #pragma unroll
    for (int i = 0; i < 5; ++i) mskL[t + 256 * i] = g[t + 256 * i];
  }
  const int lane = t & 63, w = t >> 6;
  const int lo = lane & 15, hi = lane >> 4;
  f32x4 acc[2][8] = {};
  for (int kc = 0; kc < 5; ++kc) {
    if (kc) __syncthreads();                     // MFMA(kc-1) done before restage
    // stage buf: 64 rows x 16 chunk8 = 1024 chunks
    {
      const __hip_bfloat16* base = (kc == 0)
          ? (P + (size_t)(b * SSLOT) * HD + n0)
          : (Q + (size_t)(b * UU + (kc - 1) * 64) * HD + n0);
      #pragma unroll
      for (int i = 0; i < 4; ++i) {
        int idx = t + i * 256;
        int r = idx >> 4, cc = idx & 15;
        *(short8*)&buf[r * 136 + cc * 8] =
            *(const short8*)(base + (size_t)r * HD + cc * 8);
      }
    }
    __syncthreads();
    // transpose buf -> pan: 128 n x 8 k8 = 1024 chunks
    #pragma unroll
    for (int i = 0; i < 4; ++i) {
      int idx = t + i * 256;
      int n = idx >> 3, k8 = idx & 7;
      short8 v;
      #pragma unroll
      for (int e = 0; e < 8; ++e) v[e] = buf[(k8 * 8 + e) * 136 + n];
      *(short8*)&pan[n * 72 + k8 * 8] = v;
    }
    __syncthreads();
    // MFMA: 2 kt per chunk
    #pragma unroll
    for (int kt2 = 0; kt2 < 2; ++kt2) {
      const int kt = kc * 2 + kt2;
      short8 af[2], bf[8];
      #pragma unroll
      for (int rb = 0; rb < 2; ++rb) {
        int lu = w * 32 + rb * 16 + lo;
        unsigned m = mskL[lu * 10 + kt];
        unsigned by = (m >> (hi * 8)) & 0xFFu;
        union { unsigned u[4]; short8 s; } cv;
        cv.u[0] = ((by & 1u)  ? 0x3F80u : 0u) | ((by & 2u)   ? 0x3F800000u : 0u);
        cv.u[1] = ((by & 4u)  ? 0x3F80u : 0u) | ((by & 8u)   ? 0x3F800000u : 0u);
        cv.u[2] = ((by & 16u) ? 0x3F80u : 0u) | ((by & 32u)  ? 0x3F800000u : 0u);
        cv.u[3] = ((by & 64u) ? 0x3F80u : 0u) | ((by & 128u) ? 0x3F800000u : 0u);
        af[rb] = cv.s;
      }
      #pragma unroll
      for (int cb = 0; cb < 8; ++cb) {
        int n = cb * 16 + lo;
        bf[cb] = *(const short8*)&pan[n * 72 + (kt2 * 4 + hi) * 8];
      }
      #pragma unroll
      for (int rb = 0; rb < 2; ++rb)
        #pragma unroll
        for (int cb = 0; cb < 8; ++cb)
          acc[rb][cb] = __builtin_amdgcn_mfma_f32_16x16x32_bf16(af[rb], bf[cb], acc[rb][cb], 0, 0, 0);
    }
  }
  #pragma unroll
  for (int cb = 0; cb < 8; ++cb) {
    int n = cb * 16 + lo;
    float bv = b1[n0 + n];
    #pragma unroll
    for (int rb = 0; rb < 2; ++rb) {
      #pragma unroll
      for (int j = 0; j < 4; ++j) {
        int u = b * 256 + uh * 128 + w * 32 + rb * 16 + hi * 4 + j;
        h1[(size_t)u * HD + n0 + n] = f2b(fmaxf(acc[rb][cb][j] + bv, 0.f));
      }
    }
  }
}

// ---------------------------------------------------------------------------
// K3 (round-15 verbatim): layer-2 GEMM + heads, fragment-packed B.
// ---------------------------------------------------------------------------
__global__ __launch_bounds__(256) void k_heads(
    const __hip_bfloat16* __restrict__ h1o, const __hip_bfloat16* __restrict__ h1s,
    const __hip_bfloat16* __restrict__ W2F_o, const __hip_bfloat16* __restrict__ W2F_s,
    const float* __restrict__ ob2, const float* __restrict__ sb2,
    const float* __restrict__ oW3, const float* __restrict__ ob3,
    const __hip_bfloat16* __restrict__ W3F_s, const float* __restrict__ sb3,
    const unsigned long long* __restrict__ connS,
    float* __restrict__ out) {
  const int mlp = blockIdx.y;
  const int x = blockIdx.x;
  const int blk = (x & 7) * 32 + (x >> 3);      // XCD-affine, bijective
  const int u0 = blk * 64;
  const int t = threadIdx.x, lane = t & 63, wid = t >> 6;
  const int lo = lane & 15, hi = lane >> 4;

  const __hip_bfloat16* A   = mlp ? h1s : h1o;
  const __hip_bfloat16* W2F = mlp ? W2F_s : W2F_o;
  const float* b2 = mlp ? sb2 : ob2;

  __shared__ __align__(16) char lds[32768 + 2048];
  short* As = (short*)lds;               // 64 x 256 swizzled, reused as sel
  float* part = (float*)(lds + 32768);   // [4][64][2] (mlp==0)

  #pragma unroll
  for (int i = 0; i < 8; ++i) {
    int c = t + i * 256;
    int row = c >> 5, cc = c & 31;
    *(short8*)&As[row * 256 + (cc ^ (row & 7)) * 8] =
        *(const short8*)(A + (size_t)(u0 + row) * HD + cc * 8);
  }
  __syncthreads();

  f32x4 acc2[4][4] = {};
  #pragma unroll
  for (int ks = 0; ks < 8; ++ks) {
    short8 af[4], bf[4];
    #pragma unroll
    for (int rb = 0; rb < 4; ++rb) {
      int row = rb * 16 + lo;
      int ca = ks * 4 + hi;
      af[rb] = *(const short8*)&As[row * 256 + (ca ^ (row & 7)) * 8];
    }
    #pragma unroll
    for (int cb = 0; cb < 4; ++cb) {
      bf[cb] = *(const short8*)(W2F + (size_t)((((wid * 4 + cb) * 8 + ks) * 64 + lane)) * 8);
    }
    #pragma unroll
    for (int rb = 0; rb < 4; ++rb)
      #pragma unroll
      for (int cb = 0; cb < 4; ++cb)
        acc2[rb][cb] = __builtin_amdgcn_mfma_f32_16x16x32_bf16(af[rb], bf[cb], acc2[rb][cb], 0, 0, 0);
  }
  __syncthreads();

  if (mlp == 0) {
    float p0[4][4] = {}, p1[4][4] = {};
    #pragma unroll
    for (int cb = 0; cb < 4; ++cb) {
      int n = wid * 64 + cb * 16 + lo;
      float bs = b2[n], w0 = oW3[2 * n], w1 = oW3[2 * n + 1];
      #pragma unroll
      for (int rb = 0; rb < 4; ++rb)
        #pragma unroll
        for (int j = 0; j < 4; ++j) {
          float sig = 1.0f / (1.0f + __expf(-(acc2[rb][cb][j] + bs)));
          p0[rb][j] = fmaf(sig, w0, p0[rb][j]);
          p1[rb][j] = fmaf(sig, w1, p1[rb][j]);
        }
    }
    #pragma unroll
    for (int rb = 0; rb < 4; ++rb)
      #pragma unroll
      for (int j = 0; j < 4; ++j) {
        #pragma unroll
        for (int off = 1; off < 16; off <<= 1) {
          p0[rb][j] += __shfl_xor(p0[rb][j], off, 64);
          p1[rb][j] += __shfl_xor(p1[rb][j], off, 64);
        }
        if (lo == 0) {
          int row = rb * 16 + hi * 4 + j;
          part[wid * 128 + row * 2 + 0] = p0[rb][j];
          part[wid * 128 + row * 2 + 1] = p1[rb][j];
        }
      }
    __syncthreads();
    if (t < 64) {
      float q0 = part[t * 2] + part[128 + t * 2] + part[256 + t * 2] + part[384 + t * 2] + ob3[0];
      float q1 = part[t * 2 + 1] + part[128 + t * 2 + 1] + part[256 + t * 2 + 1] + part[384 + t * 2 + 1] + ob3[1];
      float m2 = fmaxf(q0, q1);
      float e0 = __expf(q0 - m2), e1 = __expf(q1 - m2);
      float iv = 1.0f / (e0 + e1);
      float2 r; r.x = e0 * iv; r.y = e1 * iv;
      *(float2*)(out + (size_t)(u0 + t) * 2) = r;
    }
  } else {
    short* sel = As;
    #pragma unroll
    for (int cb = 0; cb < 4; ++cb) {
      int n = wid * 64 + cb * 16 + lo;
      float bs = b2[n];
      #pragma unroll
      for (int rb = 0; rb < 4; ++rb)
        #pragma unroll
        for (int j = 0; j < 4; ++j) {
          int row = rb * 16 + hi * 4 + j;
          float sig = 1.0f / (1.0f + __expf(-(acc2[rb][cb][j] + bs)));
          sel[row * 256 + ((n >> 3) ^ (row & 7)) * 8 + (n & 7)] = (short)pack2(sig, 0.f);
        }
    }
    __syncthreads();
    f32x4 acc3[4] = {};
    #pragma unroll
    for (int ks = 0; ks < 8; ++ks) {
      int row = wid * 16 + lo;
      int ca = ks * 4 + hi;
      short8 af = *(const short8*)&sel[row * 256 + (ca ^ (row & 7)) * 8];
      #pragma unroll
      for (int cb = 0; cb < 4; ++cb) {
        short8 bf = *(const short8*)(W3F_s + (size_t)(((cb * 8 + ks) * 64 + lane)) * 8);
        acc3[cb] = __builtin_amdgcn_mfma_f32_16x16x32_bf16(af, bf, acc3[cb], 0, 0, 0);
      }
    }
    float sb3n[4];
    #pragma unroll
    for (int cb = 0; cb < 4; ++cb) sb3n[cb] = sb3[cb * 16 + lo];
    const int ubase = u0 + wid * 16 + hi * 4;
    #pragma unroll
    for (int j = 0; j < 4; ++j) {
      unsigned long long m = connS[ubase + j];
      float v[4]; bool ok[4];
      float mx = -INFINITY;
      #pragma unroll
      for (int cb = 0; cb < 4; ++cb) {
        int n = cb * 16 + lo;
        ok[cb] = (m >> n) & 1ull;
        v[cb] = ok[cb] ? (acc3[cb][j] + sb3n[cb]) : -INFINITY;
        mx = fmaxf(mx, v[cb]);
      }
      #pragma unroll
      for (int off = 1; off < 16; off <<= 1) mx = fmaxf(mx, __shfl_xor(mx, off, 64));
      float e[4], ssum = 0.f;
      #pragma unroll
      for (int cb = 0; cb < 4; ++cb) {
        e[cb] = ok[cb] ? __expf(v[cb] - mx) : 0.f;
        ssum += e[cb];
      }
      #pragma unroll
      for (int off = 1; off < 16; off <<= 1) ssum += __shfl_xor(ssum, off, 64);
      float iv = 1.0f / ssum;
      #pragma unroll
      for (int cb = 0; cb < 4; ++cb) {
        int n = cb * 16 + lo;
        out[(size_t)NUSER * 2 + (size_t)(ubase + j) * SSLOT + n] = e[cb] * iv;
      }
    }
  }
}

// ---------------------------------------------------------------------------
extern "C" void kernel_launch(void* const* d_in, const int* in_sizes, int n_in,
                              void* d_out, int out_size, void* d_ws, size_t ws_size,
                              hipStream_t stream) {
  const float* x_user   = (const float*)d_in[0];
  const float* x_server = (const float*)d_in[1];
  const int*   dst_u2s  = (const int*)d_in[3];
  const int*   dst_u2u  = (const int*)d_in[5];
  const float* oW1 = (const float*)d_in[6];
  const float* ob1 = (const float*)d_in[7];
  const float* oW2 = (const float*)d_in[8];
  const float* ob2 = (const float*)d_in[9];
  const float* oW3 = (const float*)d_in[10];
  const float* ob3 = (const float*)d_in[11];
  const float* sW1 = (const float*)d_in[12];
  const float* sb1 = (const float*)d_in[13];
  const float* sW2 = (const float*)d_in[14];
  const float* sb2 = (const float*)d_in[15];
  const float* sW3 = (const float*)d_in[16];
  const float* sb3 = (const float*)d_in[17];

  char* ws = (char*)d_ws;
  unsigned long long* connS = (unsigned long long*)(ws + 0);         // 128 KB
  unsigned*       MSUW  = (unsigned*)(ws + 131072);                  // 640 KB
  __hip_bfloat16* P_o  = (__hip_bfloat16*)(ws + 786432);             // 2 MB
  __hip_bfloat16* P_s  = (__hip_bfloat16*)(ws + 2883584);            // 2 MB
  __hip_bfloat16* Q_o  = (__hip_bfloat16*)(ws + 4980736);            // 8 MB
  __hip_bfloat16* Q_s  = (__hip_bfloat16*)(ws + 13369344);           // 8 MB
  __hip_bfloat16* h1o  = (__hip_bfloat16*)(ws + 21757952);           // 8 MB
  __hip_bfloat16* h1s  = (__hip_bfloat16*)(ws + 30146560);           // 8 MB
  __hip_bfloat16* W2F_o = (__hip_bfloat16*)(ws + 38535168);          // 128 KB
  __hip_bfloat16* W2F_s = (__hip_bfloat16*)(ws + 38666240);          // 128 KB
  __hip_bfloat16* W3F_s = (__hip_bfloat16*)(ws + 38797312);          // 32 KB
  float* out = (float*)d_out;

  k_prep_pq<<<dim3(320, 9), 256, 0, stream>>>(
      dst_u2s, dst_u2u, oW2, sW2, sW3, x_user, x_server, oW1, sW1,
      connS, MSUW, W2F_o, W2F_s, W3F_s, P_o, P_s, Q_o, Q_s);
  k_h1f<<<dim3(128, 2, 2), 256, 0, stream>>>(MSUW, P_o, P_s, Q_o, Q_s,
                                             ob1, sb1, h1o, h1s);
  k_heads<<<dim3(256, 2), 256, 0, stream>>>(h1o, h1s, W2F_o, W2F_s, ob2, sb2,
                                            oW3, ob3, W3F_s, sb3, connS, out);
}

// Round 17
// 56.835 us; speedup vs baseline: 1.0143x; 1.0143x over previous
//
#include <hip/hip_runtime.h>
#include <hip/hip_bf16.h>
#include <math.h>
#include <cstdint>

#define NUSER 16384   // B*U
#define BB    64
#define UU    256
#define SSLOT 64
#define HD    256
#define KTOT  320
#define DEGS  8
#define DEGU  16

typedef __attribute__((ext_vector_type(8))) short short8;
typedef __attribute__((ext_vector_type(4))) float f32x4;

static __device__ __forceinline__ __hip_bfloat16 f2b(float x) { return __float2bfloat16(x); }
static __device__ __forceinline__ unsigned pack2(float x, float y) {
  union { __hip_bfloat16 h[2]; unsigned u; } cv;
  cv.h[0] = f2b(x); cv.h[1] = f2b(y);
  return cv.u;
}

// ---------------------------------------------------------------------------
// K1: prep (masks, fragment-packed weights) + layer-1 (round-15 champion).
// ---------------------------------------------------------------------------
__global__ __launch_bounds__(256) void k_prep_pq(
    const int* __restrict__ dst_u2s, const int* __restrict__ dst_u2u,
    const float* __restrict__ oW2, const float* __restrict__ sW2,
    const float* __restrict__ sW3,
    const float* __restrict__ xu, const float* __restrict__ xs,
    const float* __restrict__ oW1, const float* __restrict__ sW1,
    unsigned long long* __restrict__ connS, unsigned* __restrict__ MSUW,
    __hip_bfloat16* __restrict__ W2F_o, __hip_bfloat16* __restrict__ W2F_s,
    __hip_bfloat16* __restrict__ W3F_s,
    __hip_bfloat16* __restrict__ P_o, __hip_bfloat16* __restrict__ P_s,
    __hip_bfloat16* __restrict__ Q_o, __hip_bfloat16* __restrict__ Q_s) {
  const int t = threadIdx.x;
  if (blockIdx.y == 0) {
    const int blk = blockIdx.x;
    if (blk < 64) {
      const int u = blk * 256 + t;
      unsigned long long ms = 0ull;
      #pragma unroll
      for (int i = 0; i < DEGS; ++i) ms |= 1ull << (dst_u2s[u * DEGS + i] & 63);
      connS[u] = ms;
      unsigned long long m0 = 0, m1 = 0, m2 = 0, m3 = 0;
      #pragma unroll
      for (int i = 0; i < DEGU; ++i) {
        int slot = dst_u2u[u * DEGU + i] & 255;
        unsigned long long bit = 1ull << (slot & 63);
        int w = slot >> 6;
        if (w == 0) m0 |= bit; else if (w == 1) m1 |= bit;
        else if (w == 2) m2 |= bit; else m3 |= bit;
      }
      unsigned* mw = MSUW + (size_t)u * 10;
      uint2* mw2 = (uint2*)mw;
      mw2[0] = make_uint2((unsigned)ms, (unsigned)(ms >> 32));
      mw2[1] = make_uint2((unsigned)m0, (unsigned)(m0 >> 32));
      mw2[2] = make_uint2((unsigned)m1, (unsigned)(m1 >> 32));
      mw2[3] = make_uint2((unsigned)m2, (unsigned)(m2 >> 32));
      mw2[4] = make_uint2((unsigned)m3, (unsigned)(m3 >> 32));
      {
        const int n = blk;
        const int ks = t >> 5, hi = (t >> 3) & 3, e = t & 7;
        const int lane = hi * 16 + (n & 15);
        const size_t idx = (size_t)((((n >> 4) * 8 + ks) * 64 + lane)) * 8 + e;
        W3F_s[idx] = f2b(sW3[(ks * 32 + hi * 8 + e) * SSLOT + n]);
      }
    } else {
      const int n = blk - 64;
      const int ks = t >> 5, hi = (t >> 3) & 3, e = t & 7;
      const int lane = hi * 16 + (n & 15);
      const size_t idx = (size_t)((((n >> 4) * 8 + ks) * 64 + lane)) * 8 + e;
      const int k = ks * 32 + hi * 8 + e;
      W2F_o[idx] = f2b(oW2[k * HD + n]);
      W2F_s[idx] = f2b(sW2[k * HD + n]);
    }
    return;
  }
  // ---- pq body ----
  const int wg = blockIdx.x;
  const int b0 = (blockIdx.y - 1) * 8;
  __shared__ float lx[8 * 16];
  const bool isS = wg < SSLOT;
  const int slot = isS ? wg : wg - SSLOT;
  if (t < 8 * 16) {
    int b = b0 + (t >> 4), d = t & 15;
    lx[t] = isS ? xs[(b * SSLOT + slot) * 16 + d] : xu[(b * UU + slot) * 16 + d];
  }
  __syncthreads();
  float wo[16], wsv[16];
  const int rbase = isS ? slot * 16 : SSLOT * 16 + slot * 16;
  #pragma unroll
  for (int d = 0; d < 16; ++d) {
    wo[d] = oW1[(rbase + d) * HD + t];
    wsv[d] = sW1[(rbase + d) * HD + t];
  }
  __hip_bfloat16* Ro = isS ? P_o : Q_o;
  __hip_bfloat16* Rs = isS ? P_s : Q_s;
  const int rows = isS ? SSLOT : UU;
  #pragma unroll
  for (int bi = 0; bi < 8; ++bi) {
    float ao = 0.f, as = 0.f;
    #pragma unroll
    for (int q = 0; q < 4; ++q) {
      float4 x4 = *(const float4*)&lx[bi * 16 + q * 4];
      ao = fmaf(x4.x, wo[q*4+0], ao); as = fmaf(x4.x, wsv[q*4+0], as);
      ao = fmaf(x4.y, wo[q*4+1], ao); as = fmaf(x4.y, wsv[q*4+1], as);
      ao = fmaf(x4.z, wo[q*4+2], ao); as = fmaf(x4.z, wsv[q*4+2], as);
      ao = fmaf(x4.w, wo[q*4+3], ao); as = fmaf(x4.w, wsv[q*4+3], as);
    }
    Ro[((b0 + bi) * rows + slot) * HD + t] = f2b(ao);
    Rs[((b0 + bi) * rows + slot) * HD + t] = f2b(as);
  }
}

// ---------------------------------------------------------------------------
// K2: transpose P,Q -> PQT[b][n][320] via LDS (round-9 validated).
// ---------------------------------------------------------------------------
__global__ __launch_bounds__(256) void k_tr(
    const __hip_bfloat16* __restrict__ P_o, const __hip_bfloat16* __restrict__ P_s,
    const __hip_bfloat16* __restrict__ Q_o, const __hip_bfloat16* __restrict__ Q_s,
    __hip_bfloat16* __restrict__ PQT_o, __hip_bfloat16* __restrict__ PQT_s) {
  const int b = blockIdx.x, mlp = blockIdx.y, nc = blockIdx.z;
  const int n0 = nc * 64;
  const int t = threadIdx.x;
  const __hip_bfloat16* P = mlp ? P_s : P_o;
  const __hip_bfloat16* Q = mlp ? Q_s : Q_o;
  __hip_bfloat16* PQT = mlp ? PQT_s : PQT_o;
  __shared__ __align__(16) short lds[64 * 72];
  for (int kt = 0; kt < 5; ++kt) {
    const __hip_bfloat16* src = (kt == 0) ? (P + (size_t)(b * SSLOT) * HD)
                                          : (Q + (size_t)(b * UU + (kt - 1) * 64) * HD);
    const int kout = (kt == 0) ? 0 : 64 + (kt - 1) * 64;
    #pragma unroll
    for (int i = 0; i < 2; ++i) {
      int c = t + i * 256;
      int row = c >> 3, cc = c & 7;
      *(short8*)&lds[row * 72 + cc * 8] =
          *(const short8*)(src + (size_t)row * HD + n0 + cc * 8);
    }
    __syncthreads();
    #pragma unroll
    for (int i = 0; i < 2; ++i) {
      int c = t + i * 256;
      int nrow = c >> 3, kc = c & 7;
      short8 v;
      #pragma unroll
      for (int e = 0; e < 8; ++e) v[e] = lds[(kc * 8 + e) * 72 + nrow];
      *(short8*)(PQT + (size_t)(b * 256 + n0 + nrow) * KTOT + kout + kc * 8) = v;
    }
    __syncthreads();
  }
}

// ---------------------------------------------------------------------------
// K3: h1 via mask-MFMA, k-chunked 48 KB LDS (round-13 validated).
// ---------------------------------------------------------------------------
__global__ __launch_bounds__(256) void k_h1(
    const unsigned* __restrict__ MSUW,
    const __hip_bfloat16* __restrict__ PQT_o, const __hip_bfloat16* __restrict__ PQT_s,
    const float* __restrict__ ob1, const float* __restrict__ sb1,
    __hip_bfloat16* __restrict__ h1o, __hip_bfloat16* __restrict__ h1s) {
  const int b = blockIdx.x >> 1, uh = blockIdx.x & 1;
  const int mlp = blockIdx.y, nh = blockIdx.z;
  const int n0 = nh * 128;
  const int t = threadIdx.x;
  const __hip_bfloat16* PQT = mlp ? PQT_s : PQT_o;
  const float* b1 = mlp ? sb1 : ob1;
  __hip_bfloat16* h1 = mlp ? h1s : h1o;

  __shared__ __align__(16) char smem[48128];
  short* pan = (short*)smem;                   // [128][168]
  unsigned* mskL = (unsigned*)(smem + 43008);  // 1280 u32

  {
    const unsigned* g = MSUW + (size_t)(b * 256 + uh * 128) * 10;
    #pragma unroll
    for (int i = 0; i < 5; ++i) mskL[t + 256 * i] = g[t + 256 * i];
  }
  const int lane = t & 63, w = t >> 6;
  const int lo = lane & 15, hi = lane >> 4;
  f32x4 acc[2][8] = {};
  for (int kc = 0; kc < 2; ++kc) {
    if (kc) __syncthreads();
    {
      const int r = t >> 1, c4 = t & 1;
      const __hip_bfloat16* src = PQT + (size_t)(b * 256 + n0 + r) * KTOT + kc * 160;
      #pragma unroll
      for (int i = 0; i < 10; ++i) {
        int cc = c4 + 2 * i;
        *(short8*)&pan[r * 168 + cc * 8] = *(const short8*)(src + cc * 8);
      }
    }
    __syncthreads();
    #pragma unroll
    for (int kt2 = 0; kt2 < 5; ++kt2) {
      const int kt = kc * 5 + kt2;
      short8 af[2], bf[8];
      #pragma unroll
      for (int rb = 0; rb < 2; ++rb) {
        int lu = w * 32 + rb * 16 + lo;
        unsigned m = mskL[lu * 10 + kt];
        unsigned by = (m >> (hi * 8)) & 0xFFu;
        union { unsigned u[4]; short8 s; } cv;
        cv.u[0] = ((by & 1u)  ? 0x3F80u : 0u) | ((by & 2u)   ? 0x3F800000u : 0u);
        cv.u[1] = ((by & 4u)  ? 0x3F80u : 0u) | ((by & 8u)   ? 0x3F800000u : 0u);
        cv.u[2] = ((by & 16u) ? 0x3F80u : 0u) | ((by & 32u)  ? 0x3F800000u : 0u);
        cv.u[3] = ((by & 64u) ? 0x3F80u : 0u) | ((by & 128u) ? 0x3F800000u : 0u);
        af[rb] = cv.s;
      }
      #pragma unroll
      for (int cb = 0; cb < 8; ++cb) {
        int n = cb * 16 + lo;
        bf[cb] = *(const short8*)&pan[n * 168 + (kt2 * 4 + hi) * 8];
      }
      #pragma unroll
      for (int rb = 0; rb < 2; ++rb)
        #pragma unroll
        for (int cb = 0; cb < 8; ++cb)
          acc[rb][cb] = __builtin_amdgcn_mfma_f32_16x16x32_bf16(af[rb], bf[cb], acc[rb][cb], 0, 0, 0);
    }
  }
  #pragma unroll
  for (int cb = 0; cb < 8; ++cb) {
    int n = cb * 16 + lo;
    float bv = b1[n0 + n];
    #pragma unroll
    for (int rb = 0; rb < 2; ++rb) {
      #pragma unroll
      for (int j = 0; j < 4; ++j) {
        int u = b * 256 + uh * 128 + w * 32 + rb * 16 + hi * 4 + j;
        h1[(size_t)u * HD + n0 + n] = f2b(fmaxf(acc[rb][cb][j] + bv, 0.f));
      }
    }
  }
}

// ---------------------------------------------------------------------------
// K4: layer-2 GEMM + heads, M-tile 64, fragment-packed B (round-15 champion).
// ---------------------------------------------------------------------------
__global__ __launch_bounds__(256) void k_heads(
    const __hip_bfloat16* __restrict__ h1o, const __hip_bfloat16* __restrict__ h1s,
    const __hip_bfloat16* __restrict__ W2F_o, const __hip_bfloat16* __restrict__ W2F_s,
    const float* __restrict__ ob2, const float* __restrict__ sb2,
    const float* __restrict__ oW3, const float* __restrict__ ob3,
    const __hip_bfloat16* __restrict__ W3F_s, const float* __restrict__ sb3,
    const unsigned long long* __restrict__ connS,
    float* __restrict__ out) {
  const int mlp = blockIdx.y;
  const int x = blockIdx.x;
  const int blk = (x & 7) * 32 + (x >> 3);      // XCD-affine, bijective
  const int u0 = blk * 64;
  const int t = threadIdx.x, lane = t & 63, wid = t >> 6;
  const int lo = lane & 15, hi = lane >> 4;

  const __hip_bfloat16* A   = mlp ? h1s : h1o;
  const __hip_bfloat16* W2F = mlp ? W2F_s : W2F_o;
  const float* b2 = mlp ? sb2 : ob2;

  __shared__ __align__(16) char lds[32768 + 2048];
  short* As = (short*)lds;               // 64 x 256 swizzled, reused as sel
  float* part = (float*)(lds + 32768);   // [4][64][2] (mlp==0)

  #pragma unroll
  for (int i = 0; i < 8; ++i) {
    int c = t + i * 256;
    int row = c >> 5, cc = c & 31;
    *(short8*)&As[row * 256 + (cc ^ (row & 7)) * 8] =
        *(const short8*)(A + (size_t)(u0 + row) * HD + cc * 8);
  }
  __syncthreads();

  f32x4 acc2[4][4] = {};
  #pragma unroll
  for (int ks = 0; ks < 8; ++ks) {
    short8 af[4], bf[4];
    #pragma unroll
    for (int rb = 0; rb < 4; ++rb) {
      int row = rb * 16 + lo;
      int ca = ks * 4 + hi;
      af[rb] = *(const short8*)&As[row * 256 + (ca ^ (row & 7)) * 8];
    }
    #pragma unroll
    for (int cb = 0; cb < 4; ++cb) {
      bf[cb] = *(const short8*)(W2F + (size_t)((((wid * 4 + cb) * 8 + ks) * 64 + lane)) * 8);
    }
    #pragma unroll
    for (int rb = 0; rb < 4; ++rb)
      #pragma unroll
      for (int cb = 0; cb < 4; ++cb)
        acc2[rb][cb] = __builtin_amdgcn_mfma_f32_16x16x32_bf16(af[rb], bf[cb], acc2[rb][cb], 0, 0, 0);
  }
  __syncthreads();

  if (mlp == 0) {
    float p0[4][4] = {}, p1[4][4] = {};
    #pragma unroll
    for (int cb = 0; cb < 4; ++cb) {
      int n = wid * 64 + cb * 16 + lo;
      float bs = b2[n], w0 = oW3[2 * n], w1 = oW3[2 * n + 1];
      #pragma unroll
      for (int rb = 0; rb < 4; ++rb)
        #pragma unroll
        for (int j = 0; j < 4; ++j) {
          float sig = 1.0f / (1.0f + __expf(-(acc2[rb][cb][j] + bs)));
          p0[rb][j] = fmaf(sig, w0, p0[rb][j]);
          p1[rb][j] = fmaf(sig, w1, p1[rb][j]);
        }
    }
    #pragma unroll
    for (int rb = 0; rb < 4; ++rb)
      #pragma unroll
      for (int j = 0; j < 4; ++j) {
        #pragma unroll
        for (int off = 1; off < 16; off <<= 1) {
          p0[rb][j] += __shfl_xor(p0[rb][j], off, 64);
          p1[rb][j] += __shfl_xor(p1[rb][j], off, 64);
        }
        if (lo == 0) {
          int row = rb * 16 + hi * 4 + j;
          part[wid * 128 + row * 2 + 0] = p0[rb][j];
          part[wid * 128 + row * 2 + 1] = p1[rb][j];
        }
      }
    __syncthreads();
    if (t < 64) {
      float q0 = part[t * 2] + part[128 + t * 2] + part[256 + t * 2] + part[384 + t * 2] + ob3[0];
      float q1 = part[t * 2 + 1] + part[128 + t * 2 + 1] + part[256 + t * 2 + 1] + part[384 + t * 2 + 1] + ob3[1];
      float m2 = fmaxf(q0, q1);
      float e0 = __expf(q0 - m2), e1 = __expf(q1 - m2);
      float iv = 1.0f / (e0 + e1);
      float2 r; r.x = e0 * iv; r.y = e1 * iv;
      *(float2*)(out + (size_t)(u0 + t) * 2) = r;
    }
  } else {
    short* sel = As;
    #pragma unroll
    for (int cb = 0; cb < 4; ++cb) {
      int n = wid * 64 + cb * 16 + lo;
      float bs = b2[n];
      #pragma unroll
      for (int rb = 0; rb < 4; ++rb)
        #pragma unroll
        for (int j = 0; j < 4; ++j) {
          int row = rb * 16 + hi * 4 + j;
          float sig = 1.0f / (1.0f + __expf(-(acc2[rb][cb][j] + bs)));
          sel[row * 256 + ((n >> 3) ^ (row & 7)) * 8 + (n & 7)] = (short)pack2(sig, 0.f);
        }
    }
    __syncthreads();
    f32x4 acc3[4] = {};
    #pragma unroll
    for (int ks = 0; ks < 8; ++ks) {
      int row = wid * 16 + lo;
      int ca = ks * 4 + hi;
      short8 af = *(const short8*)&sel[row * 256 + (ca ^ (row & 7)) * 8];
      #pragma unroll
      for (int cb = 0; cb < 4; ++cb) {
        short8 bf = *(const short8*)(W3F_s + (size_t)(((cb * 8 + ks) * 64 + lane)) * 8);
        acc3[cb] = __builtin_amdgcn_mfma_f32_16x16x32_bf16(af, bf, acc3[cb], 0, 0, 0);
      }
    }
    float sb3n[4];
    #pragma unroll
    for (int cb = 0; cb < 4; ++cb) sb3n[cb] = sb3[cb * 16 + lo];
    const int ubase = u0 + wid * 16 + hi * 4;
    #pragma unroll
    for (int j = 0; j < 4; ++j) {
      unsigned long long m = connS[ubase + j];
      float v[4]; bool ok[4];
      float mx = -INFINITY;
      #pragma unroll
      for (int cb = 0; cb < 4; ++cb) {
        int n = cb * 16 + lo;
        ok[cb] = (m >> n) & 1ull;
        v[cb] = ok[cb] ? (acc3[cb][j] + sb3n[cb]) : -INFINITY;
        mx = fmaxf(mx, v[cb]);
      }
      #pragma unroll
      for (int off = 1; off < 16; off <<= 1) mx = fmaxf(mx, __shfl_xor(mx, off, 64));
      float e[4], ssum = 0.f;
      #pragma unroll
      for (int cb = 0; cb < 4; ++cb) {
        e[cb] = ok[cb] ? __expf(v[cb] - mx) : 0.f;
        ssum += e[cb];
      }
      #pragma unroll
      for (int off = 1; off < 16; off <<= 1) ssum += __shfl_xor(ssum, off, 64);
      float iv = 1.0f / ssum;
      #pragma unroll
      for (int cb = 0; cb < 4; ++cb) {
        int n = cb * 16 + lo;
        out[(size_t)NUSER * 2 + (size_t)(ubase + j) * SSLOT + n] = e[cb] * iv;
      }
    }
  }
}

// ---------------------------------------------------------------------------
extern "C" void kernel_launch(void* const* d_in, const int* in_sizes, int n_in,
                              void* d_out, int out_size, void* d_ws, size_t ws_size,
                              hipStream_t stream) {
  const float* x_user   = (const float*)d_in[0];
  const float* x_server = (const float*)d_in[1];
  const int*   dst_u2s  = (const int*)d_in[3];
  const int*   dst_u2u  = (const int*)d_in[5];
  const float* oW1 = (const float*)d_in[6];
  const float* ob1 = (const float*)d_in[7];
  const float* oW2 = (const float*)d_in[8];
  const float* ob2 = (const float*)d_in[9];
  const float* oW3 = (const float*)d_in[10];
  const float* ob3 = (const float*)d_in[11];
  const float* sW1 = (const float*)d_in[12];
  const float* sb1 = (const float*)d_in[13];
  const float* sW2 = (const float*)d_in[14];
  const float* sb2 = (const float*)d_in[15];
  const float* sW3 = (const float*)d_in[16];
  const float* sb3 = (const float*)d_in[17];

  char* ws = (char*)d_ws;
  unsigned long long* connS = (unsigned long long*)(ws + 0);         // 128 KB
  unsigned*       MSUW  = (unsigned*)(ws + 131072);                  // 640 KB
  __hip_bfloat16* P_o  = (__hip_bfloat16*)(ws + 786432);             // 2 MB
  __hip_bfloat16* P_s  = (__hip_bfloat16*)(ws + 2883584);            // 2 MB
  __hip_bfloat16* Q_o  = (__hip_bfloat16*)(ws + 4980736);            // 8 MB
  __hip_bfloat16* Q_s  = (__hip_bfloat16*)(ws + 13369344);           // 8 MB
  __hip_bfloat16* PQT_o = (__hip_bfloat16*)(ws + 21757952);          // 10 MB
  __hip_bfloat16* PQT_s = (__hip_bfloat16*)(ws + 32243712);          // 10 MB
  __hip_bfloat16* h1o  = (__hip_bfloat16*)(ws + 42729472);           // 8 MB
  __hip_bfloat16* h1s  = (__hip_bfloat16*)(ws + 51118080);           // 8 MB
  __hip_bfloat16* W2F_o = (__hip_bfloat16*)(ws + 59506688);          // 128 KB
  __hip_bfloat16* W2F_s = (__hip_bfloat16*)(ws + 59637760);          // 128 KB
  __hip_bfloat16* W3F_s = (__hip_bfloat16*)(ws + 59768832);          // 32 KB
  float* out = (float*)d_out;

  k_prep_pq<<<dim3(320, 9), 256, 0, stream>>>(
      dst_u2s, dst_u2u, oW2, sW2, sW3, x_user, x_server, oW1, sW1,
      connS, MSUW, W2F_o, W2F_s, W3F_s, P_o, P_s, Q_o, Q_s);
  k_tr<<<dim3(64, 2, 4), 256, 0, stream>>>(P_o, P_s, Q_o, Q_s, PQT_o, PQT_s);
  k_h1<<<dim3(128, 2, 2), 256, 0, stream>>>(MSUW, PQT_o, PQT_s, ob1, sb1, h1o, h1s);
  k_heads<<<dim3(256, 2), 256, 0, stream>>>(h1o, h1s, W2F_o, W2F_s, ob2, sb2,
                                            oW3, ob3, W3F_s, sb3, connS, out);
}